// Round 13
// baseline (342.143 us; speedup 1.0000x reference)
//
#include <hip/hip_runtime.h>
#include <hip/hip_bf16.h>

// GIN forward, MI355X. Sizes fixed by the reference.
constexpr int N_NODES  = 100000;
constexpr int N_EDGES  = 1280000;
constexpr int HDIM     = 64;
constexpr int N_GRAPHS = 128;
constexpr int N_RES    = 4;
constexpr int CAP      = 64;       // CSR slots per node (P(deg>64) ~ e-60)
constexpr int ZNODE    = N_NODES;  // zero pad row index in padded h buffers

typedef __attribute__((ext_vector_type(8))) short bf16x8;
typedef __attribute__((ext_vector_type(4))) float f32x4;

// ---- bf16 helpers (RNE) ----
__device__ __forceinline__ unsigned f2bf1(float f) {
  unsigned u = __float_as_uint(f);
  return (u + 0x7fffu + ((u >> 16) & 1u)) >> 16;
}
__device__ __forceinline__ unsigned packbf(float lo, float hi) {
  return f2bf1(lo) | (f2bf1(hi) << 16);
}
__device__ __forceinline__ float bflo(unsigned u) { return __uint_as_float(u << 16); }
__device__ __forceinline__ float bfhi(unsigned u) { return __uint_as_float(u & 0xffff0000u); }
__device__ __forceinline__ float bf2f(unsigned short h) { return __uint_as_float(((unsigned)h) << 16); }

__device__ __forceinline__ float tanh_fast(float x) {
  float xc = fminf(fmaxf(x, -15.f), 15.f);
  float e = __expf(2.f * xc);
  return __fdividef(e - 1.f, e + 1.f);
}

// ---------------- CSR build: XCD-binned single pass ----------------
constexpr int RNG = 8;
constexpr int RSZ = N_NODES / RNG;      // 12500
constexpr int CHUNKS = 128;
constexpr int CSZ = N_EDGES / CHUNKS;   // 10000

// 8 edges/thread; all predicated atomics issued before the dependent scatter
// writes so 8 atomic latencies overlap (R12: VALUBusy 3% = serialized chains).
__global__ void fill_kernel(const int* __restrict__ ei,
                            int* __restrict__ cnt, int* __restrict__ csr) {
  int b = blockIdx.x;
  int lo = (b & (RNG - 1)) * RSZ;
  int hi = lo + RSZ;
  int base = (b >> 3) * CSZ;
  for (int i = base + threadIdx.x * 8; i < base + CSZ; i += 256 * 8) {
    int4 dq0 = *(const int4*)&ei[N_EDGES + i];
    int4 dq1 = *(const int4*)&ei[N_EDGES + i + 4];
    int4 sq0 = *(const int4*)&ei[i];
    int4 sq1 = *(const int4*)&ei[i + 4];
    int d[8] = {dq0.x, dq0.y, dq0.z, dq0.w, dq1.x, dq1.y, dq1.z, dq1.w};
    int s[8] = {sq0.x, sq0.y, sq0.z, sq0.w, sq1.x, sq1.y, sq1.z, sq1.w};
    int p[8];
    bool m[8];
#pragma unroll
    for (int q = 0; q < 8; ++q) {
      m[q] = (d[q] >= lo && d[q] < hi);
      p[q] = 0;
      if (m[q]) p[q] = atomicAdd(&cnt[d[q]], 1);
    }
#pragma unroll
    for (int q = 0; q < 8; ++q) {
      if (m[q]) csr[d[q] * CAP + (p[q] & (CAP - 1))] = s[q];
    }
  }
}

// pre-write ZNODE sentinel into slots 0..15 of every row (runs BEFORE fill)
__global__ void prefill_kernel(int* __restrict__ csr) {
  int n = blockIdx.x * blockDim.x + threadIdx.x;
  if (n > N_NODES) return;
  int4 z4 = make_int4(ZNODE, ZNODE, ZNODE, ZNODE);
  int4* p = (int4*)(csr + (size_t)n * CAP);
  p[0] = z4; p[1] = z4; p[2] = z4; p[3] = z4;
}

// x (f32) -> padded bf16 buffer; pad row zero
__global__ void cvt_pad_kernel(const float* __restrict__ x, unsigned short* __restrict__ dst) {
  constexpr int TOT = (N_NODES + 1) * HDIM / 2;   // uint (bf16x2) count
  constexpr int XN  = N_NODES * HDIM / 2;
  unsigned* d = (unsigned*)dst;
  for (int i = blockIdx.x * blockDim.x + threadIdx.x; i < TOT; i += gridDim.x * blockDim.x) {
    unsigned v = 0;
    if (i < XN) { float2 f = *(const float2*)&x[i * 2]; v = packbf(f.x, f.y); }
    d[i] = v;
  }
}

// goff[g] = lower_bound(batch, g) over sorted batch ids
__global__ void goff_kernel(const int* __restrict__ batch, int* __restrict__ goff) {
  int g = threadIdx.x;
  if (g > N_GRAPHS) return;
  int lo = 0, hi = N_NODES;
  while (lo < hi) {
    int mid = (lo + hi) >> 1;
    if (batch[mid] < g) lo = mid + 1; else hi = mid;
  }
  goff[g] = lo;
}

// ---------------- pack all 10 conv weight matrices into MFMA B-fragments ----
// dst per matrix (mat = layer*2 + isW2): 8192 bf16 = hi[4096] | lo[4096].
// element e = f*512 + lane*8 + i maps to W[ks*32 + (lane>>4)*8 + i][tc*16 + (lane&15)],
// f = tc*2 + ks. Same (lane,elem)->k map is used for the A fragments.
// Layer l block: W1 at l*16384, W2 at l*16384 + 8192.
__global__ void packw_kernel(const float* __restrict__ c1W1, const float* __restrict__ c1W2,
                             const float* __restrict__ csW1, const float* __restrict__ csW2,
                             unsigned short* __restrict__ dst) {
  int idx = blockIdx.x * 256 + threadIdx.x;   // 10 * 4096
  if (idx >= 10 * 4096) return;
  int mat = idx >> 12;
  int e   = idx & 4095;
  int f    = e >> 9;
  int lane = (e >> 3) & 63;
  int i    = e & 7;
  int tc = f >> 1, ks = f & 1;
  int krow = ks * 32 + (lane >> 4) * 8 + i;
  int col  = tc * 16 + (lane & 15);
  int l = mat >> 1;
  const float* W;
  if (l == 0) W = (mat & 1) ? c1W2 : c1W1;
  else        W = ((mat & 1) ? csW2 : csW1) + (size_t)(l - 1) * 4096;
  float w = W[krow * 64 + col];
  unsigned short hi = (unsigned short)f2bf1(w);
  unsigned short lo = (unsigned short)f2bf1(w - bf2f(hi));
  unsigned short* d = dst + (size_t)mat * 8192;
  d[e] = hi;
  d[4096 + e] = lo;
}

// ---------------- fused GIN conv: 256 thr = 4 waves, 64 nodes, MFMA MLP -----
// Gather: 2-stage software pipeline (issue pass p+1's 17 row loads before
// consuming pass p) -> ~34 loads in flight per lane (R12 had VGPR=32, 1-pass
// depth). z split bf16 hi/lo -> LDS [node][k] stride 72. MLP: per wave,
// 16 nodes x 64 feats via mfma_f32_16x16x32_bf16, 3-product split, W packed.
template <bool RESID>
__global__ __launch_bounds__(256, 4)
void conv_kernel(const unsigned short* __restrict__ hin, unsigned short* __restrict__ hout,
                 const int* __restrict__ cnt, const int* __restrict__ csr,
                 const unsigned short* __restrict__ Wpk,   // layer block: W1 hi|lo, W2 hi|lo
                 const float* __restrict__ b1, const float* __restrict__ b2,
                 const float* __restrict__ gam, const float* __restrict__ bet,
                 const float* __restrict__ rm, const float* __restrict__ rv) {
  __shared__ __align__(16) unsigned short zb0[64][72];   // hi
  __shared__ __align__(16) unsigned short zb1[64][72];   // lo
  const int t   = threadIdx.x;
  const int ln  = t & 63;
  const int wid = __builtin_amdgcn_readfirstlane(t >> 6);   // 0..3
  const int lc  = ln & 31;
  const bool hiH = ln >= 32;
  const int nb  = blockIdx.x * 64;
  const unsigned* hb = (const unsigned*)hin;   // row stride 32 words

  // stage issue: compute pair (nA,nB) for pass p, load CSR slots (s_load),
  // issue 17 row loads (self + 16 neighbors) into v[17]
  auto issue = [&](int p, unsigned* v, int& onA, int& onB, int& odA, int& odB) {
    int m = wid * 16 + 2 * p;
    int nA = nb + m; if (nA > ZNODE) nA = ZNODE;
    int nB = nA + 1; if (nB > ZNODE) nB = ZNODE;
    const int* rA = csr + (size_t)nA * CAP;
    const int* rB = csr + (size_t)nB * CAP;
    int4 a0 = *(const int4*)(rA + 0), a1q = *(const int4*)(rA + 4);
    int4 a2 = *(const int4*)(rA + 8), a3q = *(const int4*)(rA + 12);
    int4 b0 = *(const int4*)(rB + 0), b1q = *(const int4*)(rB + 4);
    int4 b2q = *(const int4*)(rB + 8), b3q = *(const int4*)(rB + 12);
    odA = cnt[nA]; odB = cnt[nB];
    int self = hiH ? nB : nA;
    v[16] = hb[(size_t)self * 32 + lc];
    int i0  = hiH ? b0.x  : a0.x;   int i1  = hiH ? b0.y  : a0.y;
    int i2  = hiH ? b0.z  : a0.z;   int i3  = hiH ? b0.w  : a0.w;
    int i4  = hiH ? b1q.x : a1q.x;  int i5  = hiH ? b1q.y : a1q.y;
    int i6  = hiH ? b1q.z : a1q.z;  int i7  = hiH ? b1q.w : a1q.w;
    int i8  = hiH ? b2q.x : a2.x;   int i9  = hiH ? b2q.y : a2.y;
    int i10 = hiH ? b2q.z : a2.z;   int i11 = hiH ? b2q.w : a2.w;
    int i12 = hiH ? b3q.x : a3q.x;  int i13 = hiH ? b3q.y : a3q.y;
    int i14 = hiH ? b3q.z : a3q.z;  int i15 = hiH ? b3q.w : a3q.w;
    v[0]  = hb[(size_t)i0  * 32 + lc];  v[1]  = hb[(size_t)i1  * 32 + lc];
    v[2]  = hb[(size_t)i2  * 32 + lc];  v[3]  = hb[(size_t)i3  * 32 + lc];
    v[4]  = hb[(size_t)i4  * 32 + lc];  v[5]  = hb[(size_t)i5  * 32 + lc];
    v[6]  = hb[(size_t)i6  * 32 + lc];  v[7]  = hb[(size_t)i7  * 32 + lc];
    v[8]  = hb[(size_t)i8  * 32 + lc];  v[9]  = hb[(size_t)i9  * 32 + lc];
    v[10] = hb[(size_t)i10 * 32 + lc];  v[11] = hb[(size_t)i11 * 32 + lc];
    v[12] = hb[(size_t)i12 * 32 + lc];  v[13] = hb[(size_t)i13 * 32 + lc];
    v[14] = hb[(size_t)i14 * 32 + lc];  v[15] = hb[(size_t)i15 * 32 + lc];
    onA = nA; onB = nB;
  };

  auto consume = [&](int p, const unsigned* v, int nA, int nB, int dA, int dB) {
    float z0 = bflo(v[16]), z1 = bfhi(v[16]);
#pragma unroll
    for (int q = 0; q < 16; ++q) { z0 += bflo(v[q]); z1 += bfhi(v[q]); }
    int dS = hiH ? dB : dA;
    if (dS > 16) {
      const int* rS = csr + (size_t)(hiH ? nB : nA) * CAP;
      for (int q = 16; q < dS; ++q) {
        unsigned u = hb[(size_t)rS[q] * 32 + lc];
        z0 += bflo(u); z1 += bfhi(u);
      }
    }
    int mr = wid * 16 + 2 * p + (hiH ? 1 : 0);
    unsigned h0 = f2bf1(z0);
    float r0 = z0 - __uint_as_float(h0 << 16);
    float r1 = z1 - __uint_as_float(f2bf1(z1) << 16);
    *(unsigned*)&zb0[mr][2 * lc] = h0 | (f2bf1(z1) << 16);
    *(unsigned*)&zb1[mr][2 * lc] = f2bf1(r0) | (f2bf1(r1) << 16);
  };

  // ---- software-pipelined gather: 8 passes, 2 stages ----
  unsigned vbufA[17], vbufB[17];
  int nA0, nB0, dA0, dB0, nA1, nB1, dA1, dB1;
  issue(0, vbufA, nA0, nB0, dA0, dB0);
#pragma unroll
  for (int p = 0; p < 8; ++p) {
    if (p & 1) {
      if (p < 7) issue(p + 1, vbufA, nA0, nB0, dA0, dB0);
      consume(p, vbufB, nA1, nB1, dA1, dB1);
    } else {
      if (p < 7) issue(p + 1, vbufB, nA1, nB1, dA1, dB1);
      consume(p, vbufA, nA0, nB0, dA0, dB0);
    }
  }
  __syncthreads();    // fence: order gather LDS stores before b128 frag reads

  const int l15 = ln & 15, lg = ln >> 4;
  const int arow = 16 * wid + l15;                  // A-frag row (node-local)
  const unsigned short* W1pk = Wpk;
  const unsigned short* W2pk = Wpk + 8192;          // per-matrix block = 8192 bf16

  // ---- matvec 1: a1 = relu(z @ W1 + b1), wave-local 16 nodes x 64 feats ----
  f32x4 acc[4];
#pragma unroll
  for (int tc = 0; tc < 4; ++tc) {
    float bv = b1[tc * 16 + l15];
    acc[tc] = (f32x4){bv, bv, bv, bv};
  }
#pragma unroll
  for (int ks = 0; ks < 2; ++ks) {
    bf16x8 ah = *(const bf16x8*)&zb0[arow][lg * 8 + ks * 32];
    bf16x8 al = *(const bf16x8*)&zb1[arow][lg * 8 + ks * 32];
#pragma unroll
    for (int tc = 0; tc < 4; ++tc) {
      bf16x8 bh = *(const bf16x8*)&W1pk[(size_t)((tc * 2 + ks) * 64 + ln) * 8];
      bf16x8 bl = *(const bf16x8*)&W1pk[4096 + (size_t)((tc * 2 + ks) * 64 + ln) * 8];
      acc[tc] = __builtin_amdgcn_mfma_f32_16x16x32_bf16(ah, bh, acc[tc], 0, 0, 0);
      acc[tc] = __builtin_amdgcn_mfma_f32_16x16x32_bf16(al, bh, acc[tc], 0, 0, 0);
      acc[tc] = __builtin_amdgcn_mfma_f32_16x16x32_bf16(ah, bl, acc[tc], 0, 0, 0);
    }
  }
  __syncthreads();    // all matvec-1 A reads complete before a1 overwrite

  // ---- ReLU + split + write a1 back to zb (same wave-private rows) ----
#pragma unroll
  for (int tc = 0; tc < 4; ++tc) {
#pragma unroll
    for (int r = 0; r < 4; ++r) {
      float v = fmaxf(acc[tc][r], 0.0f);
      int node = 16 * wid + lg * 4 + r;
      int feat = tc * 16 + l15;
      unsigned short hh = (unsigned short)f2bf1(v);
      zb0[node][feat] = hh;
      zb1[node][feat] = (unsigned short)f2bf1(v - bf2f(hh));
    }
  }
  __syncthreads();    // fence: order a1 stores before matvec-2 frag reads

  // ---- matvec 2: y = a1 @ W2 + b2 ----
#pragma unroll
  for (int tc = 0; tc < 4; ++tc) {
    float bv = b2[tc * 16 + l15];
    acc[tc] = (f32x4){bv, bv, bv, bv};
  }
#pragma unroll
  for (int ks = 0; ks < 2; ++ks) {
    bf16x8 ah = *(const bf16x8*)&zb0[arow][lg * 8 + ks * 32];
    bf16x8 al = *(const bf16x8*)&zb1[arow][lg * 8 + ks * 32];
#pragma unroll
    for (int tc = 0; tc < 4; ++tc) {
      bf16x8 bh = *(const bf16x8*)&W2pk[(size_t)((tc * 2 + ks) * 64 + ln) * 8];
      bf16x8 bl = *(const bf16x8*)&W2pk[4096 + (size_t)((tc * 2 + ks) * 64 + ln) * 8];
      acc[tc] = __builtin_amdgcn_mfma_f32_16x16x32_bf16(ah, bh, acc[tc], 0, 0, 0);
      acc[tc] = __builtin_amdgcn_mfma_f32_16x16x32_bf16(al, bh, acc[tc], 0, 0, 0);
      acc[tc] = __builtin_amdgcn_mfma_f32_16x16x32_bf16(ah, bl, acc[tc], 0, 0, 0);
    }
  }

  // ---- ReLU + BN (+residual) + bf16 store ----
#pragma unroll
  for (int tc = 0; tc < 4; ++tc) {
    int feat = tc * 16 + l15;
    float sc = gam[feat] * rsqrtf(rv[feat] + 1e-5f);
    float sh = bet[feat] - rm[feat] * sc;
#pragma unroll
    for (int r = 0; r < 4; ++r) {
      int gn = nb + 16 * wid + lg * 4 + r;
      bool v = gn < N_NODES;
      int gnc = v ? gn : ZNODE;
      float y = fmaxf(acc[tc][r], 0.0f) * sc + sh;
      if (RESID) y += bf2f(hin[(size_t)gnc * 64 + feat]);
      if (v) hout[(size_t)gn * 64 + feat] = (unsigned short)f2bf1(y);
    }
  }
}

// ---------------- fused head + mean-pool partial sums (R9-proven) ----------
__global__ __launch_bounds__(512, 6)
void head_pool_kernel(const unsigned short* __restrict__ hin, float* __restrict__ out,
                      const int* __restrict__ batch,
                      const float* __restrict__ W, const float* __restrict__ b) {
  const int t   = threadIdx.x;
  const int ln  = t & 63;
  const int wid = __builtin_amdgcn_readfirstlane(t >> 6);
  const int n = blockIdx.x * 64 + ln;
  const bool valid = n < N_NODES;
  const int nn = valid ? n : ZNODE;
  const unsigned* hb = (const unsigned*)hin;

  unsigned zp[32];
#pragma unroll
  for (int cc = 0; cc < 8; ++cc) {
    uint4 u = *(const uint4*)&hb[(size_t)nn * 32 + cc * 4];
    zp[cc * 4 + 0] = u.x; zp[cc * 4 + 1] = u.y;
    zp[cc * 4 + 2] = u.z; zp[cc * 4 + 3] = u.w;
  }

  const float* Wp = W + wid * 8;
  const float* bp = b + wid * 8;
  float acc[8];
#pragma unroll
  for (int f = 0; f < 8; ++f) acc[f] = bp[f];
#pragma unroll
  for (int w = 0; w < 32; ++w) {
    float zlo = bflo(zp[w]), zhi = bfhi(zp[w]);
#pragma unroll
    for (int f = 0; f < 8; ++f) acc[f] = fmaf(zlo, Wp[(2 * w) * 64 + f], acc[f]);
#pragma unroll
    for (int f = 0; f < 8; ++f) acc[f] = fmaf(zhi, Wp[(2 * w + 1) * 64 + f], acc[f]);
  }
#pragma unroll
  for (int f = 0; f < 8; ++f) acc[f] = tanh_fast(acc[f]);

  int bg = valid ? batch[n] : -1;
  int gmax = bg;
#pragma unroll
  for (int off = 32; off >= 1; off >>= 1) gmax = max(gmax, __shfl_xor(gmax, off));
  gmax = __builtin_amdgcn_readfirstlane(gmax);
  int g0 = __builtin_amdgcn_readfirstlane(bg);

  for (int g = g0; g <= gmax; ++g) {
    float s[8];
    bool inG = (bg == g);
#pragma unroll
    for (int f = 0; f < 8; ++f) s[f] = inG ? acc[f] : 0.0f;
#pragma unroll
    for (int off = 1; off <= 32; off <<= 1) {
#pragma unroll
      for (int f = 0; f < 8; ++f) s[f] += __shfl_xor(s[f], off);
    }
    float sv = s[0];
    sv = (ln == 1) ? s[1] : sv;  sv = (ln == 2) ? s[2] : sv;
    sv = (ln == 3) ? s[3] : sv;  sv = (ln == 4) ? s[4] : sv;
    sv = (ln == 5) ? s[5] : sv;  sv = (ln == 6) ? s[6] : sv;
    sv = (ln == 7) ? s[7] : sv;
    if (ln < 8) atomicAdd(&out[g * 64 + wid * 8 + ln], sv);
  }
}

// out[g][f] /= max(count_g, 1)
__global__ void div_kernel(float* __restrict__ out, const int* __restrict__ goff) {
  int i = blockIdx.x * blockDim.x + threadIdx.x;
  if (i >= N_GRAPHS * 64) return;
  int g = i >> 6;
  int c = goff[g + 1] - goff[g];
  out[i] /= (float)max(c, 1);
}

// ---------------- launch ----------------
extern "C" void kernel_launch(void* const* d_in, const int* in_sizes, int n_in,
                              void* d_out, int out_size, void* d_ws, size_t ws_size,
                              hipStream_t stream) {
  const float* x     = (const float*)d_in[0];
  const int*   ei    = (const int*)d_in[1];
  const int*   batch = (const int*)d_in[2];
  const float* c1_W1 = (const float*)d_in[3];
  const float* c1_b1 = (const float*)d_in[4];
  const float* c1_W2 = (const float*)d_in[5];
  const float* c1_b2 = (const float*)d_in[6];
  const float* c1_g  = (const float*)d_in[7];
  const float* c1_be = (const float*)d_in[8];
  const float* c1_m  = (const float*)d_in[9];
  const float* c1_v  = (const float*)d_in[10];
  const float* cs_W1 = (const float*)d_in[11];
  const float* cs_b1 = (const float*)d_in[12];
  const float* cs_W2 = (const float*)d_in[13];
  const float* cs_b2 = (const float*)d_in[14];
  const float* cs_g  = (const float*)d_in[15];
  const float* cs_be = (const float*)d_in[16];
  const float* cs_m  = (const float*)d_in[17];
  const float* cs_v  = (const float*)d_in[18];
  const float* lin_W = (const float*)d_in[19];
  const float* lin_b = (const float*)d_in[20];
  float* out = (float*)d_out;

  size_t cur = 0;
  auto take = [&](size_t bytes) -> void* {
    void* p = (char*)d_ws + cur;
    cur += (bytes + 255) & ~(size_t)255;
    return p;
  };
  int* cnt  = (int*)take((N_NODES + 1) * sizeof(int));
  size_t zbytes = cur;                       // cnt zeroed every call
  int* goff = (int*)take((N_GRAPHS + 1) * sizeof(int));
  int* csr  = (int*)take((size_t)(N_NODES + 1) * CAP * sizeof(int));
  unsigned short* bufA = (unsigned short*)take((size_t)(N_NODES + 1) * HDIM * sizeof(unsigned short));
  unsigned short* bufB = (unsigned short*)take((size_t)(N_NODES + 1) * HDIM * sizeof(unsigned short));
  unsigned short* wpk  = (unsigned short*)take((size_t)10 * 8192 * sizeof(unsigned short));
  (void)ws_size; (void)in_sizes; (void)n_in; (void)out_size;

  hipMemsetAsync(cnt, 0, zbytes, stream);
  hipMemsetAsync(bufA + (size_t)ZNODE * HDIM, 0, HDIM * sizeof(unsigned short), stream);
  hipMemsetAsync(out, 0, N_GRAPHS * 64 * sizeof(float), stream);

  prefill_kernel<<<(N_NODES + 256) / 256, 256, 0, stream>>>(csr);
  fill_kernel<<<RNG * CHUNKS, 256, 0, stream>>>(ei, cnt, csr);
  cvt_pad_kernel<<<2048, 256, 0, stream>>>(x, bufB);   // x -> padded bf16 bufB
  goff_kernel<<<1, 256, 0, stream>>>(batch, goff);
  packw_kernel<<<160, 256, 0, stream>>>(c1_W1, c1_W2, cs_W1, cs_W2, wpk);

  const int NBLK = (N_NODES + 63) / 64;      // 1563 blocks x 256 thr (4 waves)

  // conv1: bufB(x) -> bufA  (layer l weight block at wpk + l*16384)
  conv_kernel<false><<<NBLK, 256, 0, stream>>>(bufB, bufA, cnt, csr,
      wpk, c1_b1, c1_b2, c1_g, c1_be, c1_m, c1_v);

  // 4 residual convs: A->B->A->B->A
  unsigned short* srcp = bufA;
  unsigned short* dstp = bufB;
  for (int l = 0; l < N_RES; ++l) {
    conv_kernel<true><<<NBLK, 256, 0, stream>>>(srcp, dstp, cnt, csr,
        wpk + (size_t)(l + 1) * 16384,
        cs_b1 + l * 64, cs_b2 + l * 64,
        cs_g + l * 64, cs_be + l * 64, cs_m + l * 64, cs_v + l * 64);
    unsigned short* tmp = srcp; srcp = dstp; dstp = tmp;
  }
  // final h in bufA (srcp); fused head + pool -> out, then divide by counts
  head_pool_kernel<<<NBLK, 512, 0, stream>>>(srcp, out, batch, lin_W, lin_b);
  div_kernel<<<(N_GRAPHS * 64 + 255) / 256, 256, 0, stream>>>(out, goff);
}

// Round 14
// 336.207 us; speedup vs baseline: 1.0177x; 1.0177x over previous
//
#include <hip/hip_runtime.h>
#include <hip/hip_bf16.h>

// GIN forward, MI355X. Sizes fixed by the reference.
constexpr int N_NODES  = 100000;
constexpr int N_EDGES  = 1280000;
constexpr int HDIM     = 64;
constexpr int N_GRAPHS = 128;
constexpr int N_RES    = 4;
constexpr int CAP      = 64;       // CSR slots per node (P(deg>64) ~ e-60)
constexpr int ZNODE    = N_NODES;  // zero pad row index in padded h buffers

typedef __attribute__((ext_vector_type(8))) short bf16x8;
typedef __attribute__((ext_vector_type(4))) float f32x4;

// ---- bf16 helpers (RNE) ----
__device__ __forceinline__ unsigned f2bf1(float f) {
  unsigned u = __float_as_uint(f);
  return (u + 0x7fffu + ((u >> 16) & 1u)) >> 16;
}
__device__ __forceinline__ unsigned packbf(float lo, float hi) {
  return f2bf1(lo) | (f2bf1(hi) << 16);
}
__device__ __forceinline__ float bflo(unsigned u) { return __uint_as_float(u << 16); }
__device__ __forceinline__ float bfhi(unsigned u) { return __uint_as_float(u & 0xffff0000u); }
__device__ __forceinline__ float bf2f(unsigned short h) { return __uint_as_float(((unsigned)h) << 16); }

__device__ __forceinline__ float tanh_fast(float x) {
  float xc = fminf(fmaxf(x, -15.f), 15.f);
  float e = __expf(2.f * xc);
  return __fdividef(e - 1.f, e + 1.f);
}

// ---------------- CSR build: XCD-binned single pass (R12-proven) ----------
constexpr int RNG = 8;
constexpr int RSZ = N_NODES / RNG;      // 12500
constexpr int CHUNKS = 128;
constexpr int CSZ = N_EDGES / CHUNKS;   // 10000

__global__ void fill_kernel(const int* __restrict__ ei,
                            int* __restrict__ cnt, int* __restrict__ csr) {
  int b = blockIdx.x;
  int lo = (b & (RNG - 1)) * RSZ;
  int hi = lo + RSZ;
  int base = (b >> 3) * CSZ;
  for (int i = base + threadIdx.x * 4; i < base + CSZ; i += 256 * 4) {
    int4 d4 = *(const int4*)&ei[N_EDGES + i];
    int4 s4 = *(const int4*)&ei[i];
    if (d4.x >= lo && d4.x < hi) { int p = atomicAdd(&cnt[d4.x], 1); csr[d4.x * CAP + (p & (CAP - 1))] = s4.x; }
    if (d4.y >= lo && d4.y < hi) { int p = atomicAdd(&cnt[d4.y], 1); csr[d4.y * CAP + (p & (CAP - 1))] = s4.y; }
    if (d4.z >= lo && d4.z < hi) { int p = atomicAdd(&cnt[d4.z], 1); csr[d4.z * CAP + (p & (CAP - 1))] = s4.z; }
    if (d4.w >= lo && d4.w < hi) { int p = atomicAdd(&cnt[d4.w], 1); csr[d4.w * CAP + (p & (CAP - 1))] = s4.w; }
  }
}

// ---------------- merged prep: prefill + cvt_pad + packw + goff ------------
// All four are mutually independent and independent of fill; one launch.
__global__ void prep_kernel(const float* __restrict__ x, unsigned short* __restrict__ dstx,
                            int* __restrict__ csr,
                            const int* __restrict__ batch, int* __restrict__ goff,
                            const float* __restrict__ c1W1, const float* __restrict__ c1W2,
                            const float* __restrict__ csW1, const float* __restrict__ csW2,
                            unsigned short* __restrict__ wpk) {
  int i = blockIdx.x * 256 + threadIdx.x;

  // cvt_pad: x -> padded bf16 (grid-stride)
  constexpr int TOT = (N_NODES + 1) * HDIM / 2;
  constexpr int XN  = N_NODES * HDIM / 2;
  unsigned* d = (unsigned*)dstx;
  for (int k = i; k < TOT; k += 2048 * 256) {
    unsigned v = 0;
    if (k < XN) { float2 f = *(const float2*)&x[k * 2]; v = packbf(f.x, f.y); }
    d[k] = v;
  }

  // prefill: ZNODE sentinel in slots 0..15 of every CSR row
  if (i <= N_NODES) {
    int4 z4 = make_int4(ZNODE, ZNODE, ZNODE, ZNODE);
    int4* p = (int4*)(csr + (size_t)i * CAP);
    p[0] = z4; p[1] = z4; p[2] = z4; p[3] = z4;
  }

  // packw: B-fragment pack, hi|lo split. Layer l: W1 @ l*16384, W2 @ +8192.
  if (i < 10 * 4096) {
    int mat = i >> 12;
    int e   = i & 4095;
    int f    = e >> 9;
    int lane = (e >> 3) & 63;
    int ii   = e & 7;
    int tc = f >> 1, ks = f & 1;
    int krow = ks * 32 + (lane >> 4) * 8 + ii;
    int col  = tc * 16 + (lane & 15);
    int l = mat >> 1;
    const float* W;
    if (l == 0) W = (mat & 1) ? c1W2 : c1W1;
    else        W = ((mat & 1) ? csW2 : csW1) + (size_t)(l - 1) * 4096;
    float w = W[krow * 64 + col];
    unsigned short hi = (unsigned short)f2bf1(w);
    unsigned short lo = (unsigned short)f2bf1(w - bf2f(hi));
    unsigned short* dd = wpk + (size_t)mat * 8192;
    dd[e] = hi;
    dd[4096 + e] = lo;
  }

  // goff: lower_bound over sorted batch
  if (i <= N_GRAPHS) {
    int lo = 0, hi = N_NODES;
    while (lo < hi) {
      int mid = (lo + hi) >> 1;
      if (batch[mid] < i) lo = mid + 1; else hi = mid;
    }
    goff[i] = lo;
  }
}

// ---------------- fused GIN conv: 4 waves, 64 nodes, MFMA MLP --------------
// Gather: 4 passes x 2 node-pairs -> 34 row loads in flight per wave (R12 had
// 17). launch_bounds(256,6) keeps VGPR<=85 so residency stays grid-limited
// (6.1 blocks/CU) -- R13's regression was VGPR 128 capping residency at 4.
// z split bf16 hi/lo -> LDS [node][k] stride 72. MLP: per wave, 16 nodes x
// 64 feats via mfma_f32_16x16x32_bf16, 3-product split, W pre-packed.
template <bool RESID>
__global__ __launch_bounds__(256, 6)
void conv_kernel(const unsigned short* __restrict__ hin, unsigned short* __restrict__ hout,
                 const int* __restrict__ cnt, const int* __restrict__ csr,
                 const unsigned short* __restrict__ Wpk,   // layer: W1 hi|lo, W2 hi|lo
                 const float* __restrict__ b1, const float* __restrict__ b2,
                 const float* __restrict__ gam, const float* __restrict__ bet,
                 const float* __restrict__ rm, const float* __restrict__ rv) {
  __shared__ __align__(16) unsigned short zb0[64][72];   // hi
  __shared__ __align__(16) unsigned short zb1[64][72];   // lo
  const int t   = threadIdx.x;
  const int ln  = t & 63;
  const int wid = __builtin_amdgcn_readfirstlane(t >> 6);   // 0..3
  const int lc  = ln & 31;
  const bool hiH = ln >= 32;
  const int nb  = blockIdx.x * 64;
  const unsigned* hb = (const unsigned*)hin;   // row stride 32 words

  // ---- gather: wave wid -> nodes [16w,16w+16), 4 passes x 2 pairs ----
  for (int pp = 0; pp < 4; ++pp) {
    int m = wid * 16 + 4 * pp;
    int nA0 = nb + m;     if (nA0 > ZNODE) nA0 = ZNODE;
    int nB0 = nA0 + 1;    if (nB0 > ZNODE) nB0 = ZNODE;
    int nA1 = nb + m + 2; if (nA1 > ZNODE) nA1 = ZNODE;
    int nB1 = nA1 + 1;    if (nB1 > ZNODE) nB1 = ZNODE;
    const int* rA0 = csr + (size_t)nA0 * CAP;
    const int* rB0 = csr + (size_t)nB0 * CAP;
    const int* rA1 = csr + (size_t)nA1 * CAP;
    const int* rB1 = csr + (size_t)nB1 * CAP;
    int4 a0 = *(const int4*)(rA0 + 0), a1q = *(const int4*)(rA0 + 4);
    int4 a2 = *(const int4*)(rA0 + 8), a3q = *(const int4*)(rA0 + 12);
    int4 b0 = *(const int4*)(rB0 + 0), b1q = *(const int4*)(rB0 + 4);
    int4 b2q = *(const int4*)(rB0 + 8), b3q = *(const int4*)(rB0 + 12);
    int4 c0 = *(const int4*)(rA1 + 0), c1q = *(const int4*)(rA1 + 4);
    int4 c2 = *(const int4*)(rA1 + 8), c3q = *(const int4*)(rA1 + 12);
    int4 e0 = *(const int4*)(rB1 + 0), e1q = *(const int4*)(rB1 + 4);
    int4 e2 = *(const int4*)(rB1 + 8), e3q = *(const int4*)(rB1 + 12);
    int dA0c = cnt[nA0], dB0c = cnt[nB0], dA1c = cnt[nA1], dB1c = cnt[nB1];

    int s0 = hiH ? nB0 : nA0;
    int s1 = hiH ? nB1 : nA1;
    int ia[16] = {
      hiH ? b0.x  : a0.x,  hiH ? b0.y  : a0.y,  hiH ? b0.z  : a0.z,  hiH ? b0.w  : a0.w,
      hiH ? b1q.x : a1q.x, hiH ? b1q.y : a1q.y, hiH ? b1q.z : a1q.z, hiH ? b1q.w : a1q.w,
      hiH ? b2q.x : a2.x,  hiH ? b2q.y : a2.y,  hiH ? b2q.z : a2.z,  hiH ? b2q.w : a2.w,
      hiH ? b3q.x : a3q.x, hiH ? b3q.y : a3q.y, hiH ? b3q.z : a3q.z, hiH ? b3q.w : a3q.w };
    int ja[16] = {
      hiH ? e0.x  : c0.x,  hiH ? e0.y  : c0.y,  hiH ? e0.z  : c0.z,  hiH ? e0.w  : c0.w,
      hiH ? e1q.x : c1q.x, hiH ? e1q.y : c1q.y, hiH ? e1q.z : c1q.z, hiH ? e1q.w : c1q.w,
      hiH ? e2.x  : c2.x,  hiH ? e2.y  : c2.y,  hiH ? e2.z  : c2.z,  hiH ? e2.w  : c2.w,
      hiH ? e3q.x : c3q.x, hiH ? e3q.y : c3q.y, hiH ? e3q.z : c3q.z, hiH ? e3q.w : c3q.w };

    unsigned v[17], w[17];
    v[16] = hb[(size_t)s0 * 32 + lc];
    w[16] = hb[(size_t)s1 * 32 + lc];
#pragma unroll
    for (int q = 0; q < 16; ++q) v[q] = hb[(size_t)ia[q] * 32 + lc];
#pragma unroll
    for (int q = 0; q < 16; ++q) w[q] = hb[(size_t)ja[q] * 32 + lc];

    float z0 = bflo(v[16]), z1 = bfhi(v[16]);
#pragma unroll
    for (int q = 0; q < 16; ++q) { z0 += bflo(v[q]); z1 += bfhi(v[q]); }
    float y0 = bflo(w[16]), y1 = bfhi(w[16]);
#pragma unroll
    for (int q = 0; q < 16; ++q) { y0 += bflo(w[q]); y1 += bfhi(w[q]); }

    int dS0 = hiH ? dB0c : dA0c;
    if (dS0 > 16) {
      const int* rS = hiH ? rB0 : rA0;
      for (int q = 16; q < dS0; ++q) { unsigned u = hb[(size_t)rS[q] * 32 + lc]; z0 += bflo(u); z1 += bfhi(u); }
    }
    int dS1 = hiH ? dB1c : dA1c;
    if (dS1 > 16) {
      const int* rS = hiH ? rB1 : rA1;
      for (int q = 16; q < dS1; ++q) { unsigned u = hb[(size_t)rS[q] * 32 + lc]; y0 += bflo(u); y1 += bfhi(u); }
    }

    int mr0 = m + (hiH ? 1 : 0);
    int mr1 = m + 2 + (hiH ? 1 : 0);
    unsigned h0 = f2bf1(z0);
    float r0 = z0 - __uint_as_float(h0 << 16);
    float r1 = z1 - __uint_as_float(f2bf1(z1) << 16);
    *(unsigned*)&zb0[mr0][2 * lc] = h0 | (f2bf1(z1) << 16);
    *(unsigned*)&zb1[mr0][2 * lc] = f2bf1(r0) | (f2bf1(r1) << 16);
    unsigned g0 = f2bf1(y0);
    float q0 = y0 - __uint_as_float(g0 << 16);
    float q1 = y1 - __uint_as_float(f2bf1(y1) << 16);
    *(unsigned*)&zb0[mr1][2 * lc] = g0 | (f2bf1(y1) << 16);
    *(unsigned*)&zb1[mr1][2 * lc] = f2bf1(q0) | (f2bf1(q1) << 16);
  }
  __syncthreads();    // fence: order gather LDS stores before b128 frag reads

  const int l15 = ln & 15, lg = ln >> 4;
  const int arow = 16 * wid + l15;                  // A-frag row (node-local)
  const unsigned short* W1pk = Wpk;
  const unsigned short* W2pk = Wpk + 8192;          // per-matrix block = 8192 bf16

  // ---- matvec 1: a1 = relu(z @ W1 + b1), wave-local 16 nodes x 64 feats ----
  f32x4 acc[4];
#pragma unroll
  for (int tc = 0; tc < 4; ++tc) {
    float bv = b1[tc * 16 + l15];
    acc[tc] = (f32x4){bv, bv, bv, bv};
  }
#pragma unroll
  for (int ks = 0; ks < 2; ++ks) {
    bf16x8 ah = *(const bf16x8*)&zb0[arow][lg * 8 + ks * 32];
    bf16x8 al = *(const bf16x8*)&zb1[arow][lg * 8 + ks * 32];
#pragma unroll
    for (int tc = 0; tc < 4; ++tc) {
      bf16x8 bh = *(const bf16x8*)&W1pk[(size_t)((tc * 2 + ks) * 64 + ln) * 8];
      bf16x8 bl = *(const bf16x8*)&W1pk[4096 + (size_t)((tc * 2 + ks) * 64 + ln) * 8];
      acc[tc] = __builtin_amdgcn_mfma_f32_16x16x32_bf16(ah, bh, acc[tc], 0, 0, 0);
      acc[tc] = __builtin_amdgcn_mfma_f32_16x16x32_bf16(al, bh, acc[tc], 0, 0, 0);
      acc[tc] = __builtin_amdgcn_mfma_f32_16x16x32_bf16(ah, bl, acc[tc], 0, 0, 0);
    }
  }
  __syncthreads();    // all matvec-1 A reads complete before a1 overwrite

  // ---- ReLU + split + write a1 back to zb (same wave-private rows) ----
#pragma unroll
  for (int tc = 0; tc < 4; ++tc) {
#pragma unroll
    for (int r = 0; r < 4; ++r) {
      float v = fmaxf(acc[tc][r], 0.0f);
      int node = 16 * wid + lg * 4 + r;
      int feat = tc * 16 + l15;
      unsigned short hh = (unsigned short)f2bf1(v);
      zb0[node][feat] = hh;
      zb1[node][feat] = (unsigned short)f2bf1(v - bf2f(hh));
    }
  }
  __syncthreads();    // fence: order a1 stores before matvec-2 frag reads

  // ---- matvec 2: y = a1 @ W2 + b2 ----
#pragma unroll
  for (int tc = 0; tc < 4; ++tc) {
    float bv = b2[tc * 16 + l15];
    acc[tc] = (f32x4){bv, bv, bv, bv};
  }
#pragma unroll
  for (int ks = 0; ks < 2; ++ks) {
    bf16x8 ah = *(const bf16x8*)&zb0[arow][lg * 8 + ks * 32];
    bf16x8 al = *(const bf16x8*)&zb1[arow][lg * 8 + ks * 32];
#pragma unroll
    for (int tc = 0; tc < 4; ++tc) {
      bf16x8 bh = *(const bf16x8*)&W2pk[(size_t)((tc * 2 + ks) * 64 + ln) * 8];
      bf16x8 bl = *(const bf16x8*)&W2pk[4096 + (size_t)((tc * 2 + ks) * 64 + ln) * 8];
      acc[tc] = __builtin_amdgcn_mfma_f32_16x16x32_bf16(ah, bh, acc[tc], 0, 0, 0);
      acc[tc] = __builtin_amdgcn_mfma_f32_16x16x32_bf16(al, bh, acc[tc], 0, 0, 0);
      acc[tc] = __builtin_amdgcn_mfma_f32_16x16x32_bf16(ah, bl, acc[tc], 0, 0, 0);
    }
  }

  // ---- ReLU + BN (+residual) + bf16 store ----
#pragma unroll
  for (int tc = 0; tc < 4; ++tc) {
    int feat = tc * 16 + l15;
    float sc = gam[feat] * rsqrtf(rv[feat] + 1e-5f);
    float sh = bet[feat] - rm[feat] * sc;
#pragma unroll
    for (int r = 0; r < 4; ++r) {
      int gn = nb + 16 * wid + lg * 4 + r;
      bool v = gn < N_NODES;
      int gnc = v ? gn : ZNODE;
      float y = fmaxf(acc[tc][r], 0.0f) * sc + sh;
      if (RESID) y += bf2f(hin[(size_t)gnc * 64 + feat]);
      if (v) hout[(size_t)gn * 64 + feat] = (unsigned short)f2bf1(y);
    }
  }
}

// ---------------- fused head + mean-pool partial sums (R9-proven) ----------
__global__ __launch_bounds__(512, 6)
void head_pool_kernel(const unsigned short* __restrict__ hin, float* __restrict__ out,
                      const int* __restrict__ batch,
                      const float* __restrict__ W, const float* __restrict__ b) {
  const int t   = threadIdx.x;
  const int ln  = t & 63;
  const int wid = __builtin_amdgcn_readfirstlane(t >> 6);
  const int n = blockIdx.x * 64 + ln;
  const bool valid = n < N_NODES;
  const int nn = valid ? n : ZNODE;
  const unsigned* hb = (const unsigned*)hin;

  unsigned zp[32];
#pragma unroll
  for (int cc = 0; cc < 8; ++cc) {
    uint4 u = *(const uint4*)&hb[(size_t)nn * 32 + cc * 4];
    zp[cc * 4 + 0] = u.x; zp[cc * 4 + 1] = u.y;
    zp[cc * 4 + 2] = u.z; zp[cc * 4 + 3] = u.w;
  }

  const float* Wp = W + wid * 8;
  const float* bp = b + wid * 8;
  float acc[8];
#pragma unroll
  for (int f = 0; f < 8; ++f) acc[f] = bp[f];
#pragma unroll
  for (int w = 0; w < 32; ++w) {
    float zlo = bflo(zp[w]), zhi = bfhi(zp[w]);
#pragma unroll
    for (int f = 0; f < 8; ++f) acc[f] = fmaf(zlo, Wp[(2 * w) * 64 + f], acc[f]);
#pragma unroll
    for (int f = 0; f < 8; ++f) acc[f] = fmaf(zhi, Wp[(2 * w + 1) * 64 + f], acc[f]);
  }
#pragma unroll
  for (int f = 0; f < 8; ++f) acc[f] = tanh_fast(acc[f]);

  int bg = valid ? batch[n] : -1;
  int gmax = bg;
#pragma unroll
  for (int off = 32; off >= 1; off >>= 1) gmax = max(gmax, __shfl_xor(gmax, off));
  gmax = __builtin_amdgcn_readfirstlane(gmax);
  int g0 = __builtin_amdgcn_readfirstlane(bg);

  for (int g = g0; g <= gmax; ++g) {
    float s[8];
    bool inG = (bg == g);
#pragma unroll
    for (int f = 0; f < 8; ++f) s[f] = inG ? acc[f] : 0.0f;
#pragma unroll
    for (int off = 1; off <= 32; off <<= 1) {
#pragma unroll
      for (int f = 0; f < 8; ++f) s[f] += __shfl_xor(s[f], off);
    }
    float sv = s[0];
    sv = (ln == 1) ? s[1] : sv;  sv = (ln == 2) ? s[2] : sv;
    sv = (ln == 3) ? s[3] : sv;  sv = (ln == 4) ? s[4] : sv;
    sv = (ln == 5) ? s[5] : sv;  sv = (ln == 6) ? s[6] : sv;
    sv = (ln == 7) ? s[7] : sv;
    if (ln < 8) atomicAdd(&out[g * 64 + wid * 8 + ln], sv);
  }
}

// out[g][f] /= max(count_g, 1)
__global__ void div_kernel(float* __restrict__ out, const int* __restrict__ goff) {
  int i = blockIdx.x * blockDim.x + threadIdx.x;
  if (i >= N_GRAPHS * 64) return;
  int g = i >> 6;
  int c = goff[g + 1] - goff[g];
  out[i] /= (float)max(c, 1);
}

// ---------------- launch ----------------
extern "C" void kernel_launch(void* const* d_in, const int* in_sizes, int n_in,
                              void* d_out, int out_size, void* d_ws, size_t ws_size,
                              hipStream_t stream) {
  const float* x     = (const float*)d_in[0];
  const int*   ei    = (const int*)d_in[1];
  const int*   batch = (const int*)d_in[2];
  const float* c1_W1 = (const float*)d_in[3];
  const float* c1_b1 = (const float*)d_in[4];
  const float* c1_W2 = (const float*)d_in[5];
  const float* c1_b2 = (const float*)d_in[6];
  const float* c1_g  = (const float*)d_in[7];
  const float* c1_be = (const float*)d_in[8];
  const float* c1_m  = (const float*)d_in[9];
  const float* c1_v  = (const float*)d_in[10];
  const float* cs_W1 = (const float*)d_in[11];
  const float* cs_b1 = (const float*)d_in[12];
  const float* cs_W2 = (const float*)d_in[13];
  const float* cs_b2 = (const float*)d_in[14];
  const float* cs_g  = (const float*)d_in[15];
  const float* cs_be = (const float*)d_in[16];
  const float* cs_m  = (const float*)d_in[17];
  const float* cs_v  = (const float*)d_in[18];
  const float* lin_W = (const float*)d_in[19];
  const float* lin_b = (const float*)d_in[20];
  float* out = (float*)d_out;

  size_t cur = 0;
  auto take = [&](size_t bytes) -> void* {
    void* p = (char*)d_ws + cur;
    cur += (bytes + 255) & ~(size_t)255;
    return p;
  };
  int* cnt  = (int*)take((N_NODES + 1) * sizeof(int));
  size_t zbytes = cur;                       // cnt zeroed every call
  int* goff = (int*)take((N_GRAPHS + 1) * sizeof(int));
  int* csr  = (int*)take((size_t)(N_NODES + 1) * CAP * sizeof(int));
  unsigned short* bufA = (unsigned short*)take((size_t)(N_NODES + 1) * HDIM * sizeof(unsigned short));
  unsigned short* bufB = (unsigned short*)take((size_t)(N_NODES + 1) * HDIM * sizeof(unsigned short));
  unsigned short* wpk  = (unsigned short*)take((size_t)10 * 8192 * sizeof(unsigned short));
  (void)ws_size; (void)in_sizes; (void)n_in; (void)out_size;

  hipMemsetAsync(cnt, 0, zbytes, stream);
  hipMemsetAsync(bufA + (size_t)ZNODE * HDIM, 0, HDIM * sizeof(unsigned short), stream);
  hipMemsetAsync(out, 0, N_GRAPHS * 64 * sizeof(float), stream);

  // merged prep (prefill + cvt_pad + packw + goff), then fill
  prep_kernel<<<2048, 256, 0, stream>>>(x, bufB, csr, batch, goff,
                                        c1_W1, c1_W2, cs_W1, cs_W2, wpk);
  fill_kernel<<<RNG * CHUNKS, 256, 0, stream>>>(ei, cnt, csr);

  const int NBLK = (N_NODES + 63) / 64;      // 1563 blocks x 256 thr (4 waves)

  // conv1: bufB(x) -> bufA  (layer l weight block at wpk + l*16384)
  conv_kernel<false><<<NBLK, 256, 0, stream>>>(bufB, bufA, cnt, csr,
      wpk, c1_b1, c1_b2, c1_g, c1_be, c1_m, c1_v);

  // 4 residual convs: A->B->A->B->A
  unsigned short* srcp = bufA;
  unsigned short* dstp = bufB;
  for (int l = 0; l < N_RES; ++l) {
    conv_kernel<true><<<NBLK, 256, 0, stream>>>(srcp, dstp, cnt, csr,
        wpk + (size_t)(l + 1) * 16384,
        cs_b1 + l * 64, cs_b2 + l * 64,
        cs_g + l * 64, cs_be + l * 64, cs_m + l * 64, cs_v + l * 64);
    unsigned short* tmp = srcp; srcp = dstp; dstp = tmp;
  }
  // final h in bufA (srcp); fused head + pool -> out, then divide by counts
  head_pool_kernel<<<NBLK, 512, 0, stream>>>(srcp, out, batch, lin_W, lin_b);
  div_kernel<<<(N_GRAPHS * 64 + 255) / 256, 256, 0, stream>>>(out, goff);
}

// Round 15
// 327.635 us; speedup vs baseline: 1.0443x; 1.0262x over previous
//
#include <hip/hip_runtime.h>
#include <hip/hip_bf16.h>

// GIN forward, MI355X. Sizes fixed by the reference.
constexpr int N_NODES  = 100000;
constexpr int N_EDGES  = 1280000;
constexpr int HDIM     = 64;
constexpr int N_GRAPHS = 128;
constexpr int N_RES    = 4;
constexpr int CAP      = 64;       // CSR slots per node (P(deg>64) ~ e-60)
constexpr int ZNODE    = N_NODES;  // zero pad row index in padded h buffers

typedef __attribute__((ext_vector_type(8))) short bf16x8;
typedef __attribute__((ext_vector_type(4))) float f32x4;

// ---- bf16 helpers (RNE) ----
__device__ __forceinline__ unsigned f2bf1(float f) {
  unsigned u = __float_as_uint(f);
  return (u + 0x7fffu + ((u >> 16) & 1u)) >> 16;
}
__device__ __forceinline__ unsigned packbf(float lo, float hi) {
  return f2bf1(lo) | (f2bf1(hi) << 16);
}
__device__ __forceinline__ float bflo(unsigned u) { return __uint_as_float(u << 16); }
__device__ __forceinline__ float bfhi(unsigned u) { return __uint_as_float(u & 0xffff0000u); }
__device__ __forceinline__ float bf2f(unsigned short h) { return __uint_as_float(((unsigned)h) << 16); }

__device__ __forceinline__ float tanh_fast(float x) {
  float xc = fminf(fmaxf(x, -15.f), 15.f);
  float e = __expf(2.f * xc);
  return __fdividef(e - 1.f, e + 1.f);
}

// ---------------- CSR build: XCD-binned single pass (R12-proven) ----------
constexpr int RNG = 8;
constexpr int RSZ = N_NODES / RNG;      // 12500
constexpr int CHUNKS = 128;
constexpr int CSZ = N_EDGES / CHUNKS;   // 10000

__global__ void fill_kernel(const int* __restrict__ ei,
                            int* __restrict__ cnt, int* __restrict__ csr) {
  int b = blockIdx.x;
  int lo = (b & (RNG - 1)) * RSZ;
  int hi = lo + RSZ;
  int base = (b >> 3) * CSZ;
  for (int i = base + threadIdx.x * 4; i < base + CSZ; i += 256 * 4) {
    int4 d4 = *(const int4*)&ei[N_EDGES + i];
    int4 s4 = *(const int4*)&ei[i];
    if (d4.x >= lo && d4.x < hi) { int p = atomicAdd(&cnt[d4.x], 1); csr[d4.x * CAP + (p & (CAP - 1))] = s4.x; }
    if (d4.y >= lo && d4.y < hi) { int p = atomicAdd(&cnt[d4.y], 1); csr[d4.y * CAP + (p & (CAP - 1))] = s4.y; }
    if (d4.z >= lo && d4.z < hi) { int p = atomicAdd(&cnt[d4.z], 1); csr[d4.z * CAP + (p & (CAP - 1))] = s4.z; }
    if (d4.w >= lo && d4.w < hi) { int p = atomicAdd(&cnt[d4.w], 1); csr[d4.w * CAP + (p & (CAP - 1))] = s4.w; }
  }
}

// ---------------- merged prep: prefill + cvt_pad + packw + goff ------------
__global__ void prep_kernel(const float* __restrict__ x, unsigned short* __restrict__ dstx,
                            int* __restrict__ csr,
                            const int* __restrict__ batch, int* __restrict__ goff,
                            const float* __restrict__ c1W1, const float* __restrict__ c1W2,
                            const float* __restrict__ csW1, const float* __restrict__ csW2,
                            unsigned short* __restrict__ wpk) {
  int i = blockIdx.x * 256 + threadIdx.x;

  // cvt_pad: x -> padded bf16 (grid-stride)
  constexpr int TOT = (N_NODES + 1) * HDIM / 2;
  constexpr int XN  = N_NODES * HDIM / 2;
  unsigned* d = (unsigned*)dstx;
  for (int k = i; k < TOT; k += 2048 * 256) {
    unsigned v = 0;
    if (k < XN) { float2 f = *(const float2*)&x[k * 2]; v = packbf(f.x, f.y); }
    d[k] = v;
  }

  // prefill: ZNODE sentinel in slots 0..15 of every CSR row
  if (i <= N_NODES) {
    int4 z4 = make_int4(ZNODE, ZNODE, ZNODE, ZNODE);
    int4* p = (int4*)(csr + (size_t)i * CAP);
    p[0] = z4; p[1] = z4; p[2] = z4; p[3] = z4;
  }

  // packw: B-fragment pack, hi|lo split. Layer l: W1 @ l*16384, W2 @ +8192.
  if (i < 10 * 4096) {
    int mat = i >> 12;
    int e   = i & 4095;
    int f    = e >> 9;
    int lane = (e >> 3) & 63;
    int ii   = e & 7;
    int tc = f >> 1, ks = f & 1;
    int krow = ks * 32 + (lane >> 4) * 8 + ii;
    int col  = tc * 16 + (lane & 15);
    int l = mat >> 1;
    const float* W;
    if (l == 0) W = (mat & 1) ? c1W2 : c1W1;
    else        W = ((mat & 1) ? csW2 : csW1) + (size_t)(l - 1) * 4096;
    float w = W[krow * 64 + col];
    unsigned short hi = (unsigned short)f2bf1(w);
    unsigned short lo = (unsigned short)f2bf1(w - bf2f(hi));
    unsigned short* dd = wpk + (size_t)mat * 8192;
    dd[e] = hi;
    dd[4096 + e] = lo;
  }

  // goff: lower_bound over sorted batch
  if (i <= N_GRAPHS) {
    int lo = 0, hi = N_NODES;
    while (lo < hi) {
      int mid = (lo + hi) >> 1;
      if (batch[mid] < i) lo = mid + 1; else hi = mid;
    }
    goff[i] = lo;
  }
}

// ---------------- fused GIN conv: 128 thr = 2 waves, 16 nodes, MFMA MLP ----
// R15: more waves at fixed pipeline depth. 16 nodes/wave only yields 6250
// waves (24.4/CU, grid-limited); 8 nodes/wave doubles to 12500 waves -> full
// 32 waves/CU. Per-wave gather = R12's proven pair-pass scheme, 4 passes.
// MFMA tile = 16 rows shared by the block's 2 waves (both compute the full
// tile; a1-writeback and stores predicated by row-half). Barriers are now
// cross-wave load-bearing.
template <bool RESID>
__global__ __launch_bounds__(128, 8)
void conv_kernel(const unsigned short* __restrict__ hin, unsigned short* __restrict__ hout,
                 const int* __restrict__ cnt, const int* __restrict__ csr,
                 const unsigned short* __restrict__ Wpk,   // layer: W1 hi|lo, W2 hi|lo
                 const float* __restrict__ b1, const float* __restrict__ b2,
                 const float* __restrict__ gam, const float* __restrict__ bet,
                 const float* __restrict__ rm, const float* __restrict__ rv) {
  __shared__ __align__(16) unsigned short zb0[16][72];   // hi
  __shared__ __align__(16) unsigned short zb1[16][72];   // lo
  const int t   = threadIdx.x;
  const int ln  = t & 63;
  const int wid = __builtin_amdgcn_readfirstlane(t >> 6);   // 0..1
  const int lc  = ln & 31;
  const bool hiH = ln >= 32;
  const int nb  = blockIdx.x * 16;             // 6250 blocks x 16 nodes
  const unsigned* hb = (const unsigned*)hin;   // row stride 32 words

  // ---- gather: wave wid -> block-local nodes [8*wid, 8*wid+8), 4 pairs ----
  for (int p = 0; p < 4; ++p) {
    int m = wid * 8 + 2 * p;                   // block-local node
    int nA = nb + m; if (nA > ZNODE) nA = ZNODE;
    int nB = nA + 1; if (nB > ZNODE) nB = ZNODE;
    const int* rA = csr + (size_t)nA * CAP;
    const int* rB = csr + (size_t)nB * CAP;
    int4 a0 = *(const int4*)(rA + 0), a1q = *(const int4*)(rA + 4);
    int4 a2 = *(const int4*)(rA + 8), a3q = *(const int4*)(rA + 12);
    int4 b0 = *(const int4*)(rB + 0), b1q = *(const int4*)(rB + 4);
    int4 b2q = *(const int4*)(rB + 8), b3q = *(const int4*)(rB + 12);
    int dA = cnt[nA], dB = cnt[nB];

    int self = hiH ? nB : nA;
    float z0, z1;
    { unsigned u = hb[(size_t)self * 32 + lc]; z0 = bflo(u); z1 = bfhi(u); }
    int i0  = hiH ? b0.x  : a0.x;   int i1  = hiH ? b0.y  : a0.y;
    int i2  = hiH ? b0.z  : a0.z;   int i3  = hiH ? b0.w  : a0.w;
    int i4  = hiH ? b1q.x : a1q.x;  int i5  = hiH ? b1q.y : a1q.y;
    int i6  = hiH ? b1q.z : a1q.z;  int i7  = hiH ? b1q.w : a1q.w;
    int i8  = hiH ? b2q.x : a2.x;   int i9  = hiH ? b2q.y : a2.y;
    int i10 = hiH ? b2q.z : a2.z;   int i11 = hiH ? b2q.w : a2.w;
    int i12 = hiH ? b3q.x : a3q.x;  int i13 = hiH ? b3q.y : a3q.y;
    int i14 = hiH ? b3q.z : a3q.z;  int i15 = hiH ? b3q.w : a3q.w;
#define GACC(ix) { unsigned u = hb[(size_t)(ix) * 32 + lc]; z0 += bflo(u); z1 += bfhi(u); }
    GACC(i0)  GACC(i1)  GACC(i2)  GACC(i3)
    GACC(i4)  GACC(i5)  GACC(i6)  GACC(i7)
    GACC(i8)  GACC(i9)  GACC(i10) GACC(i11)
    GACC(i12) GACC(i13) GACC(i14) GACC(i15)
#undef GACC
    if (dA > 16 && !hiH)
      for (int q = 16; q < dA; ++q) { unsigned u = hb[(size_t)rA[q] * 32 + lc]; z0 += bflo(u); z1 += bfhi(u); }
    if (dB > 16 && hiH)
      for (int q = 16; q < dB; ++q) { unsigned u = hb[(size_t)rB[q] * 32 + lc]; z0 += bflo(u); z1 += bfhi(u); }
    int mr = m + (hiH ? 1 : 0);
    unsigned h0 = f2bf1(z0);
    float r0 = z0 - __uint_as_float(h0 << 16);
    float r1 = z1 - __uint_as_float(f2bf1(z1) << 16);
    *(unsigned*)&zb0[mr][2 * lc] = h0 | (f2bf1(z1) << 16);
    *(unsigned*)&zb1[mr][2 * lc] = f2bf1(r0) | (f2bf1(r1) << 16);
  }
  __syncthreads();    // cross-wave: both halves of the 16-node tile ready

  const int l15 = ln & 15, lg = ln >> 4;
  const int arow = l15;                             // block-local node 0..15
  const unsigned short* W1pk = Wpk;
  const unsigned short* W2pk = Wpk + 8192;          // per-matrix block = 8192 bf16

  // ---- matvec 1: a1 = relu(z @ W1 + b1); both waves compute full tile ----
  f32x4 acc[4];
#pragma unroll
  for (int tc = 0; tc < 4; ++tc) {
    float bv = b1[tc * 16 + l15];
    acc[tc] = (f32x4){bv, bv, bv, bv};
  }
#pragma unroll
  for (int ks = 0; ks < 2; ++ks) {
    bf16x8 ah = *(const bf16x8*)&zb0[arow][lg * 8 + ks * 32];
    bf16x8 al = *(const bf16x8*)&zb1[arow][lg * 8 + ks * 32];
#pragma unroll
    for (int tc = 0; tc < 4; ++tc) {
      bf16x8 bh = *(const bf16x8*)&W1pk[(size_t)((tc * 2 + ks) * 64 + ln) * 8];
      bf16x8 bl = *(const bf16x8*)&W1pk[4096 + (size_t)((tc * 2 + ks) * 64 + ln) * 8];
      acc[tc] = __builtin_amdgcn_mfma_f32_16x16x32_bf16(ah, bh, acc[tc], 0, 0, 0);
      acc[tc] = __builtin_amdgcn_mfma_f32_16x16x32_bf16(al, bh, acc[tc], 0, 0, 0);
      acc[tc] = __builtin_amdgcn_mfma_f32_16x16x32_bf16(ah, bl, acc[tc], 0, 0, 0);
    }
  }
  __syncthreads();    // all matvec-1 A reads complete before a1 overwrite

  // ---- ReLU + split + write a1 back (each wave writes its row half) ----
#pragma unroll
  for (int tc = 0; tc < 4; ++tc) {
#pragma unroll
    for (int r = 0; r < 4; ++r) {
      int node = lg * 4 + r;                   // block-local row 0..15
      if ((node >> 3) == wid) {
        float v = fmaxf(acc[tc][r], 0.0f);
        int feat = tc * 16 + l15;
        unsigned short hh = (unsigned short)f2bf1(v);
        zb0[node][feat] = hh;
        zb1[node][feat] = (unsigned short)f2bf1(v - bf2f(hh));
      }
    }
  }
  __syncthreads();    // a1 fully written before matvec-2 frag reads

  // ---- matvec 2: y = a1 @ W2 + b2 ----
#pragma unroll
  for (int tc = 0; tc < 4; ++tc) {
    float bv = b2[tc * 16 + l15];
    acc[tc] = (f32x4){bv, bv, bv, bv};
  }
#pragma unroll
  for (int ks = 0; ks < 2; ++ks) {
    bf16x8 ah = *(const bf16x8*)&zb0[arow][lg * 8 + ks * 32];
    bf16x8 al = *(const bf16x8*)&zb1[arow][lg * 8 + ks * 32];
#pragma unroll
    for (int tc = 0; tc < 4; ++tc) {
      bf16x8 bh = *(const bf16x8*)&W2pk[(size_t)((tc * 2 + ks) * 64 + ln) * 8];
      bf16x8 bl = *(const bf16x8*)&W2pk[4096 + (size_t)((tc * 2 + ks) * 64 + ln) * 8];
      acc[tc] = __builtin_amdgcn_mfma_f32_16x16x32_bf16(ah, bh, acc[tc], 0, 0, 0);
      acc[tc] = __builtin_amdgcn_mfma_f32_16x16x32_bf16(al, bh, acc[tc], 0, 0, 0);
      acc[tc] = __builtin_amdgcn_mfma_f32_16x16x32_bf16(ah, bl, acc[tc], 0, 0, 0);
    }
  }

  // ---- ReLU + BN (+residual) + bf16 store (each wave stores its half) ----
#pragma unroll
  for (int tc = 0; tc < 4; ++tc) {
    int feat = tc * 16 + l15;
    float sc = gam[feat] * rsqrtf(rv[feat] + 1e-5f);
    float sh = bet[feat] - rm[feat] * sc;
#pragma unroll
    for (int r = 0; r < 4; ++r) {
      int node = lg * 4 + r;
      int gn = nb + node;
      bool v = ((node >> 3) == wid) && (gn < N_NODES);
      int gnc = (gn < N_NODES) ? gn : ZNODE;
      float y = fmaxf(acc[tc][r], 0.0f) * sc + sh;
      if (RESID) y += bf2f(hin[(size_t)gnc * 64 + feat]);
      if (v) hout[(size_t)gn * 64 + feat] = (unsigned short)f2bf1(y);
    }
  }
}

// ---------------- fused head + mean-pool partial sums (R9-proven) ----------
__global__ __launch_bounds__(512, 6)
void head_pool_kernel(const unsigned short* __restrict__ hin, float* __restrict__ out,
                      const int* __restrict__ batch,
                      const float* __restrict__ W, const float* __restrict__ b) {
  const int t   = threadIdx.x;
  const int ln  = t & 63;
  const int wid = __builtin_amdgcn_readfirstlane(t >> 6);
  const int n = blockIdx.x * 64 + ln;
  const bool valid = n < N_NODES;
  const int nn = valid ? n : ZNODE;
  const unsigned* hb = (const unsigned*)hin;

  unsigned zp[32];
#pragma unroll
  for (int cc = 0; cc < 8; ++cc) {
    uint4 u = *(const uint4*)&hb[(size_t)nn * 32 + cc * 4];
    zp[cc * 4 + 0] = u.x; zp[cc * 4 + 1] = u.y;
    zp[cc * 4 + 2] = u.z; zp[cc * 4 + 3] = u.w;
  }

  const float* Wp = W + wid * 8;
  const float* bp = b + wid * 8;
  float acc[8];
#pragma unroll
  for (int f = 0; f < 8; ++f) acc[f] = bp[f];
#pragma unroll
  for (int w = 0; w < 32; ++w) {
    float zlo = bflo(zp[w]), zhi = bfhi(zp[w]);
#pragma unroll
    for (int f = 0; f < 8; ++f) acc[f] = fmaf(zlo, Wp[(2 * w) * 64 + f], acc[f]);
#pragma unroll
    for (int f = 0; f < 8; ++f) acc[f] = fmaf(zhi, Wp[(2 * w + 1) * 64 + f], acc[f]);
  }
#pragma unroll
  for (int f = 0; f < 8; ++f) acc[f] = tanh_fast(acc[f]);

  int bg = valid ? batch[n] : -1;
  int gmax = bg;
#pragma unroll
  for (int off = 32; off >= 1; off >>= 1) gmax = max(gmax, __shfl_xor(gmax, off));
  gmax = __builtin_amdgcn_readfirstlane(gmax);
  int g0 = __builtin_amdgcn_readfirstlane(bg);

  for (int g = g0; g <= gmax; ++g) {
    float s[8];
    bool inG = (bg == g);
#pragma unroll
    for (int f = 0; f < 8; ++f) s[f] = inG ? acc[f] : 0.0f;
#pragma unroll
    for (int off = 1; off <= 32; off <<= 1) {
#pragma unroll
      for (int f = 0; f < 8; ++f) s[f] += __shfl_xor(s[f], off);
    }
    float sv = s[0];
    sv = (ln == 1) ? s[1] : sv;  sv = (ln == 2) ? s[2] : sv;
    sv = (ln == 3) ? s[3] : sv;  sv = (ln == 4) ? s[4] : sv;
    sv = (ln == 5) ? s[5] : sv;  sv = (ln == 6) ? s[6] : sv;
    sv = (ln == 7) ? s[7] : sv;
    if (ln < 8) atomicAdd(&out[g * 64 + wid * 8 + ln], sv);
  }
}

// out[g][f] /= max(count_g, 1)
__global__ void div_kernel(float* __restrict__ out, const int* __restrict__ goff) {
  int i = blockIdx.x * blockDim.x + threadIdx.x;
  if (i >= N_GRAPHS * 64) return;
  int g = i >> 6;
  int c = goff[g + 1] - goff[g];
  out[i] /= (float)max(c, 1);
}

// ---------------- launch ----------------
extern "C" void kernel_launch(void* const* d_in, const int* in_sizes, int n_in,
                              void* d_out, int out_size, void* d_ws, size_t ws_size,
                              hipStream_t stream) {
  const float* x     = (const float*)d_in[0];
  const int*   ei    = (const int*)d_in[1];
  const int*   batch = (const int*)d_in[2];
  const float* c1_W1 = (const float*)d_in[3];
  const float* c1_b1 = (const float*)d_in[4];
  const float* c1_W2 = (const float*)d_in[5];
  const float* c1_b2 = (const float*)d_in[6];
  const float* c1_g  = (const float*)d_in[7];
  const float* c1_be = (const float*)d_in[8];
  const float* c1_m  = (const float*)d_in[9];
  const float* c1_v  = (const float*)d_in[10];
  const float* cs_W1 = (const float*)d_in[11];
  const float* cs_b1 = (const float*)d_in[12];
  const float* cs_W2 = (const float*)d_in[13];
  const float* cs_b2 = (const float*)d_in[14];
  const float* cs_g  = (const float*)d_in[15];
  const float* cs_be = (const float*)d_in[16];
  const float* cs_m  = (const float*)d_in[17];
  const float* cs_v  = (const float*)d_in[18];
  const float* lin_W = (const float*)d_in[19];
  const float* lin_b = (const float*)d_in[20];
  float* out = (float*)d_out;

  size_t cur = 0;
  auto take = [&](size_t bytes) -> void* {
    void* p = (char*)d_ws + cur;
    cur += (bytes + 255) & ~(size_t)255;
    return p;
  };
  int* cnt  = (int*)take((N_NODES + 1) * sizeof(int));
  size_t zbytes = cur;                       // cnt zeroed every call
  int* goff = (int*)take((N_GRAPHS + 1) * sizeof(int));
  int* csr  = (int*)take((size_t)(N_NODES + 1) * CAP * sizeof(int));
  unsigned short* bufA = (unsigned short*)take((size_t)(N_NODES + 1) * HDIM * sizeof(unsigned short));
  unsigned short* bufB = (unsigned short*)take((size_t)(N_NODES + 1) * HDIM * sizeof(unsigned short));
  unsigned short* wpk  = (unsigned short*)take((size_t)10 * 8192 * sizeof(unsigned short));
  (void)ws_size; (void)in_sizes; (void)n_in; (void)out_size;

  hipMemsetAsync(cnt, 0, zbytes, stream);
  hipMemsetAsync(bufA + (size_t)ZNODE * HDIM, 0, HDIM * sizeof(unsigned short), stream);
  hipMemsetAsync(out, 0, N_GRAPHS * 64 * sizeof(float), stream);

  // merged prep (prefill + cvt_pad + packw + goff), then fill
  prep_kernel<<<2048, 256, 0, stream>>>(x, bufB, csr, batch, goff,
                                        c1_W1, c1_W2, cs_W1, cs_W2, wpk);
  fill_kernel<<<RNG * CHUNKS, 256, 0, stream>>>(ei, cnt, csr);

  const int NBLK = N_NODES / 16;             // 6250 blocks x 128 thr (2 waves)

  // conv1: bufB(x) -> bufA  (layer l weight block at wpk + l*16384)
  conv_kernel<false><<<NBLK, 128, 0, stream>>>(bufB, bufA, cnt, csr,
      wpk, c1_b1, c1_b2, c1_g, c1_be, c1_m, c1_v);

  // 4 residual convs: A->B->A->B->A
  unsigned short* srcp = bufA;
  unsigned short* dstp = bufB;
  for (int l = 0; l < N_RES; ++l) {
    conv_kernel<true><<<NBLK, 128, 0, stream>>>(srcp, dstp, cnt, csr,
        wpk + (size_t)(l + 1) * 16384,
        cs_b1 + l * 64, cs_b2 + l * 64,
        cs_g + l * 64, cs_be + l * 64, cs_m + l * 64, cs_v + l * 64);
    unsigned short* tmp = srcp; srcp = dstp; dstp = tmp;
  }
  // final h in bufA (srcp); fused head + pool -> out, then divide by counts
  head_pool_kernel<<<(N_NODES + 63) / 64, 512, 0, stream>>>(srcp, out, batch, lin_W, lin_b);
  div_kernel<<<(N_GRAPHS * 64 + 255) / 256, 256, 0, stream>>>(out, goff);
}

// Round 16
// 287.453 us; speedup vs baseline: 1.1903x; 1.1398x over previous
//
#include <hip/hip_runtime.h>
#include <hip/hip_bf16.h>

// GIN forward, MI355X. Sizes fixed by the reference.
constexpr int N_NODES  = 100000;
constexpr int N_EDGES  = 1280000;
constexpr int HDIM     = 64;
constexpr int N_GRAPHS = 128;
constexpr int N_RES    = 4;
constexpr int CAP      = 64;       // CSR slots per node (P(deg>64) ~ e-60)
constexpr int ZNODE    = N_NODES;  // zero pad row index in padded h buffers

typedef __attribute__((ext_vector_type(8))) short bf16x8;
typedef __attribute__((ext_vector_type(4))) float f32x4;

// ---- bf16 helpers (RNE) ----
__device__ __forceinline__ unsigned f2bf1(float f) {
  unsigned u = __float_as_uint(f);
  return (u + 0x7fffu + ((u >> 16) & 1u)) >> 16;
}
__device__ __forceinline__ unsigned packbf(float lo, float hi) {
  return f2bf1(lo) | (f2bf1(hi) << 16);
}
__device__ __forceinline__ float bflo(unsigned u) { return __uint_as_float(u << 16); }
__device__ __forceinline__ float bfhi(unsigned u) { return __uint_as_float(u & 0xffff0000u); }
__device__ __forceinline__ float bf2f(unsigned short h) { return __uint_as_float(((unsigned)h) << 16); }

__device__ __forceinline__ float tanh_fast(float x) {
  float xc = fminf(fmaxf(x, -15.f), 15.f);
  float e = __expf(2.f * xc);
  return __fdividef(e - 1.f, e + 1.f);
}

// ---------------- CSR build: XCD-binned single pass (R12-proven) ----------
constexpr int RNG = 8;
constexpr int RSZ = N_NODES / RNG;      // 12500
constexpr int CHUNKS = 128;
constexpr int CSZ = N_EDGES / CHUNKS;   // 10000

__global__ void fill_kernel(const int* __restrict__ ei,
                            int* __restrict__ cnt, int* __restrict__ csr) {
  int b = blockIdx.x;
  int lo = (b & (RNG - 1)) * RSZ;
  int hi = lo + RSZ;
  int base = (b >> 3) * CSZ;
  for (int i = base + threadIdx.x * 4; i < base + CSZ; i += 256 * 4) {
    int4 d4 = *(const int4*)&ei[N_EDGES + i];
    int4 s4 = *(const int4*)&ei[i];
    if (d4.x >= lo && d4.x < hi) { int p = atomicAdd(&cnt[d4.x], 1); csr[d4.x * CAP + (p & (CAP - 1))] = s4.x; }
    if (d4.y >= lo && d4.y < hi) { int p = atomicAdd(&cnt[d4.y], 1); csr[d4.y * CAP + (p & (CAP - 1))] = s4.y; }
    if (d4.z >= lo && d4.z < hi) { int p = atomicAdd(&cnt[d4.z], 1); csr[d4.z * CAP + (p & (CAP - 1))] = s4.z; }
    if (d4.w >= lo && d4.w < hi) { int p = atomicAdd(&cnt[d4.w], 1); csr[d4.w * CAP + (p & (CAP - 1))] = s4.w; }
  }
}

// ---------------- merged prep: prefill + cvt_pad + packw + goff ------------
// All four mutually independent and independent of fill; one launch.
__global__ void prep_kernel(const float* __restrict__ x, unsigned short* __restrict__ dstx,
                            int* __restrict__ csr,
                            const int* __restrict__ batch, int* __restrict__ goff,
                            const float* __restrict__ c1W1, const float* __restrict__ c1W2,
                            const float* __restrict__ csW1, const float* __restrict__ csW2,
                            unsigned short* __restrict__ wpk) {
  int i = blockIdx.x * 256 + threadIdx.x;

  // cvt_pad: x -> padded bf16 (grid-stride)
  constexpr int TOT = (N_NODES + 1) * HDIM / 2;
  constexpr int XN  = N_NODES * HDIM / 2;
  unsigned* d = (unsigned*)dstx;
  for (int k = i; k < TOT; k += 2048 * 256) {
    unsigned v = 0;
    if (k < XN) { float2 f = *(const float2*)&x[k * 2]; v = packbf(f.x, f.y); }
    d[k] = v;
  }

  // prefill: ZNODE sentinel in slots 0..15 of every CSR row
  if (i <= N_NODES) {
    int4 z4 = make_int4(ZNODE, ZNODE, ZNODE, ZNODE);
    int4* p = (int4*)(csr + (size_t)i * CAP);
    p[0] = z4; p[1] = z4; p[2] = z4; p[3] = z4;
  }

  // packw: B-fragment pack, hi|lo split. Layer l: W1 @ l*16384, W2 @ +8192.
  if (i < 10 * 4096) {
    int mat = i >> 12;
    int e   = i & 4095;
    int f    = e >> 9;
    int lane = (e >> 3) & 63;
    int ii   = e & 7;
    int tc = f >> 1, ks = f & 1;
    int krow = ks * 32 + (lane >> 4) * 8 + ii;
    int col  = tc * 16 + (lane & 15);
    int l = mat >> 1;
    const float* W;
    if (l == 0) W = (mat & 1) ? c1W2 : c1W1;
    else        W = ((mat & 1) ? csW2 : csW1) + (size_t)(l - 1) * 4096;
    float w = W[krow * 64 + col];
    unsigned short hi = (unsigned short)f2bf1(w);
    unsigned short lo = (unsigned short)f2bf1(w - bf2f(hi));
    unsigned short* dd = wpk + (size_t)mat * 8192;
    dd[e] = hi;
    dd[4096 + e] = lo;
  }

  // goff: lower_bound over sorted batch
  if (i <= N_GRAPHS) {
    int lo = 0, hi = N_NODES;
    while (lo < hi) {
      int mid = (lo + hi) >> 1;
      if (batch[mid] < i) lo = mid + 1; else hi = mid;
    }
    goff[i] = lo;
  }
}

// ---------------- fused GIN conv: R12-exact (empirical optimum) ------------
// 256 thr = 4 waves, 64 nodes. Gather: 8 sequential pair-passes, half-wave
// per node, lane = 2 features bf16x2 (whole-row coalesced loads), CSR slots
// s_load'ed, ZNODE sentinel. Measured saturation: 3 attempts to add
// concurrency (R13 depth / R14 width / R15 waves) all regressed -> gather is
// memory-system (L3/fabric random-access) bound at ~5.5 TB/s effective.
// z split bf16 hi/lo -> LDS [node][k] stride 72. MLP: per wave 16 nodes x 64
// feats via mfma_f32_16x16x32_bf16, 3-product split, W pre-packed B-frags.
template <bool RESID>
__global__ __launch_bounds__(256, 6)
void conv_kernel(const unsigned short* __restrict__ hin, unsigned short* __restrict__ hout,
                 const int* __restrict__ cnt, const int* __restrict__ csr,
                 const unsigned short* __restrict__ Wpk,   // layer: W1 hi|lo, W2 hi|lo
                 const float* __restrict__ b1, const float* __restrict__ b2,
                 const float* __restrict__ gam, const float* __restrict__ bet,
                 const float* __restrict__ rm, const float* __restrict__ rv) {
  __shared__ __align__(16) unsigned short zb0[64][72];   // hi
  __shared__ __align__(16) unsigned short zb1[64][72];   // lo
  const int t   = threadIdx.x;
  const int ln  = t & 63;
  const int wid = __builtin_amdgcn_readfirstlane(t >> 6);   // 0..3
  const int lc  = ln & 31;
  const bool hiH = ln >= 32;
  const int nb  = blockIdx.x * 64;
  const unsigned* hb = (const unsigned*)hin;   // row stride 32 words

  // ---- gather: wave wid -> local nodes [16*wid, 16*wid+16), 8 pairs ----
  for (int p = 0; p < 8; ++p) {
    int m = wid * 16 + 2 * p;
    int nA = nb + m; if (nA > ZNODE) nA = ZNODE;
    int nB = nA + 1; if (nB > ZNODE) nB = ZNODE;
    const int* rA = csr + (size_t)nA * CAP;
    const int* rB = csr + (size_t)nB * CAP;
    int4 a0 = *(const int4*)(rA + 0), a1q = *(const int4*)(rA + 4);
    int4 a2 = *(const int4*)(rA + 8), a3q = *(const int4*)(rA + 12);
    int4 b0 = *(const int4*)(rB + 0), b1q = *(const int4*)(rB + 4);
    int4 b2q = *(const int4*)(rB + 8), b3q = *(const int4*)(rB + 12);
    int dA = cnt[nA], dB = cnt[nB];

    int self = hiH ? nB : nA;
    float z0, z1;
    { unsigned u = hb[(size_t)self * 32 + lc]; z0 = bflo(u); z1 = bfhi(u); }
    int i0  = hiH ? b0.x  : a0.x;   int i1  = hiH ? b0.y  : a0.y;
    int i2  = hiH ? b0.z  : a0.z;   int i3  = hiH ? b0.w  : a0.w;
    int i4  = hiH ? b1q.x : a1q.x;  int i5  = hiH ? b1q.y : a1q.y;
    int i6  = hiH ? b1q.z : a1q.z;  int i7  = hiH ? b1q.w : a1q.w;
    int i8  = hiH ? b2q.x : a2.x;   int i9  = hiH ? b2q.y : a2.y;
    int i10 = hiH ? b2q.z : a2.z;   int i11 = hiH ? b2q.w : a2.w;
    int i12 = hiH ? b3q.x : a3q.x;  int i13 = hiH ? b3q.y : a3q.y;
    int i14 = hiH ? b3q.z : a3q.z;  int i15 = hiH ? b3q.w : a3q.w;
#define GACC(ix) { unsigned u = hb[(size_t)(ix) * 32 + lc]; z0 += bflo(u); z1 += bfhi(u); }
    GACC(i0)  GACC(i1)  GACC(i2)  GACC(i3)
    GACC(i4)  GACC(i5)  GACC(i6)  GACC(i7)
    GACC(i8)  GACC(i9)  GACC(i10) GACC(i11)
    GACC(i12) GACC(i13) GACC(i14) GACC(i15)
#undef GACC
    if (dA > 16 && !hiH)
      for (int q = 16; q < dA; ++q) { unsigned u = hb[(size_t)rA[q] * 32 + lc]; z0 += bflo(u); z1 += bfhi(u); }
    if (dB > 16 && hiH)
      for (int q = 16; q < dB; ++q) { unsigned u = hb[(size_t)rB[q] * 32 + lc]; z0 += bflo(u); z1 += bfhi(u); }
    int mr = m + (hiH ? 1 : 0);
    unsigned h0 = f2bf1(z0);
    float r0 = z0 - __uint_as_float(h0 << 16);
    float r1 = z1 - __uint_as_float(f2bf1(z1) << 16);
    *(unsigned*)&zb0[mr][2 * lc] = h0 | (f2bf1(z1) << 16);
    *(unsigned*)&zb1[mr][2 * lc] = f2bf1(r0) | (f2bf1(r1) << 16);
  }
  __syncthreads();    // fence: order gather LDS stores before b128 frag reads

  const int l15 = ln & 15, lg = ln >> 4;
  const int arow = 16 * wid + l15;                  // A-frag row (node-local)
  const unsigned short* W1pk = Wpk;
  const unsigned short* W2pk = Wpk + 8192;          // per-matrix block = 8192 bf16

  // ---- matvec 1: a1 = relu(z @ W1 + b1), wave-local 16 nodes x 64 feats ----
  f32x4 acc[4];
#pragma unroll
  for (int tc = 0; tc < 4; ++tc) {
    float bv = b1[tc * 16 + l15];
    acc[tc] = (f32x4){bv, bv, bv, bv};
  }
#pragma unroll
  for (int ks = 0; ks < 2; ++ks) {
    bf16x8 ah = *(const bf16x8*)&zb0[arow][lg * 8 + ks * 32];
    bf16x8 al = *(const bf16x8*)&zb1[arow][lg * 8 + ks * 32];
#pragma unroll
    for (int tc = 0; tc < 4; ++tc) {
      bf16x8 bh = *(const bf16x8*)&W1pk[(size_t)((tc * 2 + ks) * 64 + ln) * 8];
      bf16x8 bl = *(const bf16x8*)&W1pk[4096 + (size_t)((tc * 2 + ks) * 64 + ln) * 8];
      acc[tc] = __builtin_amdgcn_mfma_f32_16x16x32_bf16(ah, bh, acc[tc], 0, 0, 0);
      acc[tc] = __builtin_amdgcn_mfma_f32_16x16x32_bf16(al, bh, acc[tc], 0, 0, 0);
      acc[tc] = __builtin_amdgcn_mfma_f32_16x16x32_bf16(ah, bl, acc[tc], 0, 0, 0);
    }
  }
  __syncthreads();    // all matvec-1 A reads complete before a1 overwrite

  // ---- ReLU + split + write a1 back to zb (same wave-private rows) ----
#pragma unroll
  for (int tc = 0; tc < 4; ++tc) {
#pragma unroll
    for (int r = 0; r < 4; ++r) {
      float v = fmaxf(acc[tc][r], 0.0f);
      int node = 16 * wid + lg * 4 + r;
      int feat = tc * 16 + l15;
      unsigned short hh = (unsigned short)f2bf1(v);
      zb0[node][feat] = hh;
      zb1[node][feat] = (unsigned short)f2bf1(v - bf2f(hh));
    }
  }
  __syncthreads();    // fence: order a1 stores before matvec-2 frag reads

  // ---- matvec 2: y = a1 @ W2 + b2 ----
#pragma unroll
  for (int tc = 0; tc < 4; ++tc) {
    float bv = b2[tc * 16 + l15];
    acc[tc] = (f32x4){bv, bv, bv, bv};
  }
#pragma unroll
  for (int ks = 0; ks < 2; ++ks) {
    bf16x8 ah = *(const bf16x8*)&zb0[arow][lg * 8 + ks * 32];
    bf16x8 al = *(const bf16x8*)&zb1[arow][lg * 8 + ks * 32];
#pragma unroll
    for (int tc = 0; tc < 4; ++tc) {
      bf16x8 bh = *(const bf16x8*)&W2pk[(size_t)((tc * 2 + ks) * 64 + ln) * 8];
      bf16x8 bl = *(const bf16x8*)&W2pk[4096 + (size_t)((tc * 2 + ks) * 64 + ln) * 8];
      acc[tc] = __builtin_amdgcn_mfma_f32_16x16x32_bf16(ah, bh, acc[tc], 0, 0, 0);
      acc[tc] = __builtin_amdgcn_mfma_f32_16x16x32_bf16(al, bh, acc[tc], 0, 0, 0);
      acc[tc] = __builtin_amdgcn_mfma_f32_16x16x32_bf16(ah, bl, acc[tc], 0, 0, 0);
    }
  }

  // ---- ReLU + BN (+residual) + bf16 store ----
#pragma unroll
  for (int tc = 0; tc < 4; ++tc) {
    int feat = tc * 16 + l15;
    float sc = gam[feat] * rsqrtf(rv[feat] + 1e-5f);
    float sh = bet[feat] - rm[feat] * sc;
#pragma unroll
    for (int r = 0; r < 4; ++r) {
      int gn = nb + 16 * wid + lg * 4 + r;
      bool v = gn < N_NODES;
      int gnc = v ? gn : ZNODE;
      float y = fmaxf(acc[tc][r], 0.0f) * sc + sh;
      if (RESID) y += bf2f(hin[(size_t)gnc * 64 + feat]);
      if (v) hout[(size_t)gn * 64 + feat] = (unsigned short)f2bf1(y);
    }
  }
}

// ---------------- fused head + mean-pool partial sums (R9-proven) ----------
__global__ __launch_bounds__(512, 6)
void head_pool_kernel(const unsigned short* __restrict__ hin, float* __restrict__ out,
                      const int* __restrict__ batch,
                      const float* __restrict__ W, const float* __restrict__ b) {
  const int t   = threadIdx.x;
  const int ln  = t & 63;
  const int wid = __builtin_amdgcn_readfirstlane(t >> 6);
  const int n = blockIdx.x * 64 + ln;
  const bool valid = n < N_NODES;
  const int nn = valid ? n : ZNODE;
  const unsigned* hb = (const unsigned*)hin;

  unsigned zp[32];
#pragma unroll
  for (int cc = 0; cc < 8; ++cc) {
    uint4 u = *(const uint4*)&hb[(size_t)nn * 32 + cc * 4];
    zp[cc * 4 + 0] = u.x; zp[cc * 4 + 1] = u.y;
    zp[cc * 4 + 2] = u.z; zp[cc * 4 + 3] = u.w;
  }

  const float* Wp = W + wid * 8;
  const float* bp = b + wid * 8;
  float acc[8];
#pragma unroll
  for (int f = 0; f < 8; ++f) acc[f] = bp[f];
#pragma unroll
  for (int w = 0; w < 32; ++w) {
    float zlo = bflo(zp[w]), zhi = bfhi(zp[w]);
#pragma unroll
    for (int f = 0; f < 8; ++f) acc[f] = fmaf(zlo, Wp[(2 * w) * 64 + f], acc[f]);
#pragma unroll
    for (int f = 0; f < 8; ++f) acc[f] = fmaf(zhi, Wp[(2 * w + 1) * 64 + f], acc[f]);
  }
#pragma unroll
  for (int f = 0; f < 8; ++f) acc[f] = tanh_fast(acc[f]);

  int bg = valid ? batch[n] : -1;
  int gmax = bg;
#pragma unroll
  for (int off = 32; off >= 1; off >>= 1) gmax = max(gmax, __shfl_xor(gmax, off));
  gmax = __builtin_amdgcn_readfirstlane(gmax);
  int g0 = __builtin_amdgcn_readfirstlane(bg);

  for (int g = g0; g <= gmax; ++g) {
    float s[8];
    bool inG = (bg == g);
#pragma unroll
    for (int f = 0; f < 8; ++f) s[f] = inG ? acc[f] : 0.0f;
#pragma unroll
    for (int off = 1; off <= 32; off <<= 1) {
#pragma unroll
      for (int f = 0; f < 8; ++f) s[f] += __shfl_xor(s[f], off);
    }
    float sv = s[0];
    sv = (ln == 1) ? s[1] : sv;  sv = (ln == 2) ? s[2] : sv;
    sv = (ln == 3) ? s[3] : sv;  sv = (ln == 4) ? s[4] : sv;
    sv = (ln == 5) ? s[5] : sv;  sv = (ln == 6) ? s[6] : sv;
    sv = (ln == 7) ? s[7] : sv;
    if (ln < 8) atomicAdd(&out[g * 64 + wid * 8 + ln], sv);
  }
}

// out[g][f] /= max(count_g, 1)
__global__ void div_kernel(float* __restrict__ out, const int* __restrict__ goff) {
  int i = blockIdx.x * blockDim.x + threadIdx.x;
  if (i >= N_GRAPHS * 64) return;
  int g = i >> 6;
  int c = goff[g + 1] - goff[g];
  out[i] /= (float)max(c, 1);
}

// ---------------- launch ----------------
extern "C" void kernel_launch(void* const* d_in, const int* in_sizes, int n_in,
                              void* d_out, int out_size, void* d_ws, size_t ws_size,
                              hipStream_t stream) {
  const float* x     = (const float*)d_in[0];
  const int*   ei    = (const int*)d_in[1];
  const int*   batch = (const int*)d_in[2];
  const float* c1_W1 = (const float*)d_in[3];
  const float* c1_b1 = (const float*)d_in[4];
  const float* c1_W2 = (const float*)d_in[5];
  const float* c1_b2 = (const float*)d_in[6];
  const float* c1_g  = (const float*)d_in[7];
  const float* c1_be = (const float*)d_in[8];
  const float* c1_m  = (const float*)d_in[9];
  const float* c1_v  = (const float*)d_in[10];
  const float* cs_W1 = (const float*)d_in[11];
  const float* cs_b1 = (const float*)d_in[12];
  const float* cs_W2 = (const float*)d_in[13];
  const float* cs_b2 = (const float*)d_in[14];
  const float* cs_g  = (const float*)d_in[15];
  const float* cs_be = (const float*)d_in[16];
  const float* cs_m  = (const float*)d_in[17];
  const float* cs_v  = (const float*)d_in[18];
  const float* lin_W = (const float*)d_in[19];
  const float* lin_b = (const float*)d_in[20];
  float* out = (float*)d_out;

  size_t cur = 0;
  auto take = [&](size_t bytes) -> void* {
    void* p = (char*)d_ws + cur;
    cur += (bytes + 255) & ~(size_t)255;
    return p;
  };
  int* cnt  = (int*)take((N_NODES + 1) * sizeof(int));
  size_t zbytes = cur;                       // cnt zeroed every call
  int* goff = (int*)take((N_GRAPHS + 1) * sizeof(int));
  int* csr  = (int*)take((size_t)(N_NODES + 1) * CAP * sizeof(int));
  unsigned short* bufA = (unsigned short*)take((size_t)(N_NODES + 1) * HDIM * sizeof(unsigned short));
  unsigned short* bufB = (unsigned short*)take((size_t)(N_NODES + 1) * HDIM * sizeof(unsigned short));
  unsigned short* wpk  = (unsigned short*)take((size_t)10 * 8192 * sizeof(unsigned short));
  (void)ws_size; (void)in_sizes; (void)n_in; (void)out_size;

  hipMemsetAsync(cnt, 0, zbytes, stream);
  hipMemsetAsync(bufA + (size_t)ZNODE * HDIM, 0, HDIM * sizeof(unsigned short), stream);
  hipMemsetAsync(out, 0, N_GRAPHS * 64 * sizeof(float), stream);

  // merged prep (prefill + cvt_pad + packw + goff), then fill
  prep_kernel<<<2048, 256, 0, stream>>>(x, bufB, csr, batch, goff,
                                        c1_W1, c1_W2, cs_W1, cs_W2, wpk);
  fill_kernel<<<RNG * CHUNKS, 256, 0, stream>>>(ei, cnt, csr);

  const int NBLK = (N_NODES + 63) / 64;      // 1563 blocks x 256 thr (4 waves)

  // conv1: bufB(x) -> bufA  (layer l weight block at wpk + l*16384)
  conv_kernel<false><<<NBLK, 256, 0, stream>>>(bufB, bufA, cnt, csr,
      wpk, c1_b1, c1_b2, c1_g, c1_be, c1_m, c1_v);

  // 4 residual convs: A->B->A->B->A
  unsigned short* srcp = bufA;
  unsigned short* dstp = bufB;
  for (int l = 0; l < N_RES; ++l) {
    conv_kernel<true><<<NBLK, 256, 0, stream>>>(srcp, dstp, cnt, csr,
        wpk + (size_t)(l + 1) * 16384,
        cs_b1 + l * 64, cs_b2 + l * 64,
        cs_g + l * 64, cs_be + l * 64, cs_m + l * 64, cs_v + l * 64);
    unsigned short* tmp = srcp; srcp = dstp; dstp = tmp;
  }
  // final h in bufA (srcp); fused head + pool -> out, then divide by counts
  head_pool_kernel<<<NBLK, 512, 0, stream>>>(srcp, out, batch, lin_W, lin_b);
  div_kernel<<<(N_GRAPHS * 64 + 255) / 256, 256, 0, stream>>>(out, goff);
}